// Round 15
// baseline (288.186 us; speedup 1.0000x reference)
//
#include <hip/hip_runtime.h>

#define N_IN 256
#define N_OUT 64
#define NEG_SLOPE 0.01f
#define BSHIFT 8
#define BSIZE 256      // dsts per bucket
#define MAXBUCK 512    // supports n_nodes <= 131072
#define CAP 5120       // LDS edge-staging capacity (mean 4090, >11 sigma margin)

typedef __attribute__((ext_vector_type(8))) short short8v;   // 8 bf16
typedef __attribute__((ext_vector_type(4))) float float4v;   // MFMA acc

__device__ inline short f32_to_bf16_rtne(float f) {
    unsigned u = __float_as_uint(f);
    unsigned r = (u + 0x7FFFu + ((u >> 16) & 1u)) >> 16;
    return (short)r;
}
__device__ inline float bf16_to_f32(short s) {
    return __uint_as_float(((unsigned)(unsigned short)s) << 16);
}

// ---------------------------------------------------------------------------
// Kernel 1: z = h @ W.T via bf16 MFMA, fused logits s_node/d_node. (unchanged)
// ---------------------------------------------------------------------------
constexpr int GM = 64;
constexpr int KP = 264;

__global__ __launch_bounds__(256) void gemm_zsd_mfma(
    const float* __restrict__ h, const float* __restrict__ W,
    const float* __restrict__ A,
    unsigned short* __restrict__ zb, float* __restrict__ s_node, float* __restrict__ d_node,
    int n_nodes)
{
    __shared__ short hA[GM * KP];
    __shared__ short wB[N_OUT * KP];
    const int t = threadIdx.x;
    const int row0 = blockIdx.x * GM;

    for (int j = 0; j < 8; ++j) {
        const int f  = j * 256 + t;
        const int r  = f >> 5;
        const int c8 = f & 31;

        int grow = row0 + r;
        if (grow >= n_nodes) grow = n_nodes - 1;
        const float4* ph = reinterpret_cast<const float4*>(h + (size_t)grow * N_IN + c8 * 8);
        float4 h0 = ph[0], h1 = ph[1];
        short8v pkh;
        pkh[0] = f32_to_bf16_rtne(h0.x); pkh[1] = f32_to_bf16_rtne(h0.y);
        pkh[2] = f32_to_bf16_rtne(h0.z); pkh[3] = f32_to_bf16_rtne(h0.w);
        pkh[4] = f32_to_bf16_rtne(h1.x); pkh[5] = f32_to_bf16_rtne(h1.y);
        pkh[6] = f32_to_bf16_rtne(h1.z); pkh[7] = f32_to_bf16_rtne(h1.w);
        *reinterpret_cast<short8v*>(&hA[r * KP + c8 * 8]) = pkh;

        const float4* pw = reinterpret_cast<const float4*>(W + (size_t)r * N_IN + c8 * 8);
        float4 w0 = pw[0], w1 = pw[1];
        short8v pkw;
        pkw[0] = f32_to_bf16_rtne(w0.x); pkw[1] = f32_to_bf16_rtne(w0.y);
        pkw[2] = f32_to_bf16_rtne(w0.z); pkw[3] = f32_to_bf16_rtne(w0.w);
        pkw[4] = f32_to_bf16_rtne(w1.x); pkw[5] = f32_to_bf16_rtne(w1.y);
        pkw[6] = f32_to_bf16_rtne(w1.z); pkw[7] = f32_to_bf16_rtne(w1.w);
        *reinterpret_cast<short8v*>(&wB[r * KP + c8 * 8]) = pkw;
    }
    __syncthreads();

    const int w  = t >> 6;
    const int l  = t & 63;
    const int lr = l & 15;
    const int lk = l >> 4;

    float4v acc[4] = {{0.f,0.f,0.f,0.f},{0.f,0.f,0.f,0.f},
                      {0.f,0.f,0.f,0.f},{0.f,0.f,0.f,0.f}};

    for (int kk = 0; kk < 8; ++kk) {
        const int kbase = kk * 32 + lk * 8;
        const short8v a = *reinterpret_cast<const short8v*>(&hA[(w * 16 + lr) * KP + kbase]);
#pragma unroll
        for (int n = 0; n < 4; ++n) {
            const short8v b = *reinterpret_cast<const short8v*>(&wB[(n * 16 + lr) * KP + kbase]);
            acc[n] = __builtin_amdgcn_mfma_f32_16x16x32_bf16(a, b, acc[n], 0, 0, 0);
        }
    }

    float as[4], ad[4];
#pragma unroll
    for (int n = 0; n < 4; ++n) {
        as[n] = A[n * 16 + lr];
        ad[n] = A[N_OUT + n * 16 + lr];
    }

    float sv[4] = {0.f,0.f,0.f,0.f}, dv[4] = {0.f,0.f,0.f,0.f};
#pragma unroll
    for (int n = 0; n < 4; ++n) {
#pragma unroll
        for (int r = 0; r < 4; ++r) {
            const float v = acc[n][r];
            const int grow = row0 + w * 16 + lk * 4 + r;
            if (grow < n_nodes)
                zb[(size_t)grow * N_OUT + n * 16 + lr] = (unsigned short)f32_to_bf16_rtne(v);
            sv[r] = fmaf(v, as[n], sv[r]);
            dv[r] = fmaf(v, ad[n], dv[r]);
        }
    }
#pragma unroll
    for (int off = 1; off < 16; off <<= 1) {
#pragma unroll
        for (int r = 0; r < 4; ++r) {
            sv[r] += __shfl_xor(sv[r], off);
            dv[r] += __shfl_xor(dv[r], off);
        }
    }
    if (lr == 0) {
#pragma unroll
        for (int r = 0; r < 4; ++r) {
            const int grow = row0 + w * 16 + lk * 4 + r;
            if (grow < n_nodes) { s_node[grow] = sv[r]; d_node[grow] = dv[r]; }
        }
    }
}

// ---------------------------------------------------------------------------
// Kernel 2: bucket histogram of dst>>8 (LDS-aggregated; bcount pre-zeroed)
// ---------------------------------------------------------------------------
__global__ __launch_bounds__(256) void hist_bucket(
    const int* __restrict__ dst, int* __restrict__ bcount, int n_edges)
{
    __shared__ int cnt[MAXBUCK];
    const int t = threadIdx.x;
    for (int i = t; i < MAXBUCK; i += 256) cnt[i] = 0;
    __syncthreads();
    int i = blockIdx.x * 256 + t;
    const int stride = gridDim.x * 256;
    for (; i < n_edges; i += stride)
        atomicAdd(&cnt[dst[i] >> BSHIFT], 1);
    __syncthreads();
    for (int j = t; j < MAXBUCK; j += 256)
        if (cnt[j]) atomicAdd(&bcount[j], cnt[j]);
}

// ---------------------------------------------------------------------------
// Kernel 3: exclusive scan of bucket counts -> bbase[0..nbuck] + cursor copy
// ---------------------------------------------------------------------------
__global__ __launch_bounds__(1024) void scan_buckets(
    const int* __restrict__ bcount, int* __restrict__ bbase,
    int* __restrict__ bcursor, int nbuck, int n_edges)
{
    __shared__ int tmp[1024];
    const int t = threadIdx.x;
    const int v = (t < nbuck) ? bcount[t] : 0;
    tmp[t] = v;
    __syncthreads();
    for (int off = 1; off < 1024; off <<= 1) {
        int x = (t >= off) ? tmp[t - off] : 0;
        __syncthreads();
        tmp[t] += x;
        __syncthreads();
    }
    if (t < nbuck) {
        const int excl = tmp[t] - v;
        bbase[t] = excl;
        bcursor[t] = excl;
    }
    if (t == 0) bbase[nbuck] = n_edges;
}

// ---------------------------------------------------------------------------
// Kernel 4: bucket scatter -> {(dlow<<23)|src, p} in bucket order.
// Block-private runs keep line writers block-local (no cross-XCD writeback).
// ---------------------------------------------------------------------------
__global__ __launch_bounds__(256) void bucket_scatter(
    const int* __restrict__ src, const int* __restrict__ dst,
    const float* __restrict__ s_node, const float* __restrict__ d_node,
    int* __restrict__ bcursor, int2* __restrict__ ebuf, int n_edges, int nbuck)
{
    __shared__ int cnt[MAXBUCK];
    __shared__ int wcur[MAXBUCK];
    const int t = threadIdx.x;
    const int chunk = (n_edges + gridDim.x - 1) / gridDim.x;
    const int lo = blockIdx.x * chunk;
    const int hi = min(lo + chunk, n_edges);

    for (int i = t; i < MAXBUCK; i += 256) cnt[i] = 0;
    __syncthreads();
    for (int i = lo + t; i < hi; i += 256)
        atomicAdd(&cnt[dst[i] >> BSHIFT], 1);
    __syncthreads();
    for (int i = t; i < nbuck; i += 256)
        wcur[i] = cnt[i] ? atomicAdd(&bcursor[i], cnt[i]) : 0;
    __syncthreads();
    for (int i = lo + t; i < hi; i += 256) {
        const int d = dst[i];
        const int s = src[i];
        float e = s_node[s] + d_node[d];
        e = (e >= 0.f) ? e : NEG_SLOPE * e;
        const float pe = __expf(e);
        const int b = d >> BSHIFT;
        const int pos = atomicAdd(&wcur[b], 1);
        ebuf[pos] = make_int2(((d & (BSIZE - 1)) << 23) | s, __float_as_int(pe));
    }
}

// ---------------------------------------------------------------------------
// Kernel 5 (merged bin+gather): one block per bucket. Stage the bucket's
// edges in LDS, bin by dst (count/scan/LDS-scatter), then gather z rows
// straight from the LDS-sorted edges. Eliminates the ebuf2+segend global
// round trip. Fallback to global binning via ebuf2 if a bucket exceeds CAP.
// ---------------------------------------------------------------------------
__global__ __launch_bounds__(1024) void bucket_gather(
    const int2* __restrict__ ebuf, const int* __restrict__ bbase,
    int2* __restrict__ ebuf2, const unsigned short* __restrict__ zb,
    float* __restrict__ out, int n_nodes)
{
    __shared__ int2 sedge[CAP];
    __shared__ int dcnt[BSIZE];
    __shared__ int dscan[BSIZE];
    __shared__ int dcur[BSIZE];
    const int t = threadIdx.x;
    const int b = blockIdx.x;
    const int lo = bbase[b];
    const int hi = bbase[b + 1];
    const int total = hi - lo;

    // --- per-dst count ---
    if (t < BSIZE) dcnt[t] = 0;
    __syncthreads();
    for (int i = lo + t; i < hi; i += 1024)
        atomicAdd(&dcnt[((unsigned)ebuf[i].x) >> 23], 1);
    __syncthreads();
    // --- inclusive scan (local offsets) ---
    if (t < BSIZE) dscan[t] = dcnt[t];
    __syncthreads();
    for (int off = 1; off < BSIZE; off <<= 1) {
        int x = (t < BSIZE && t >= off) ? dscan[t - off] : 0;
        __syncthreads();
        if (t < BSIZE) dscan[t] += x;
        __syncthreads();
    }
    if (t < BSIZE) dcur[t] = dscan[t] - dcnt[t];
    __syncthreads();

    // --- bin into LDS (or global fallback) ---
    const int2* eptr;
    if (total <= CAP) {
        for (int i = lo + t; i < hi; i += 1024) {
            const int2 e = ebuf[i];
            const unsigned x = (unsigned)e.x;
            const int pos = atomicAdd(&dcur[x >> 23], 1);
            sedge[pos] = make_int2((int)(x & 0x7FFFFFu), e.y);
        }
        eptr = (const int2*)sedge;
    } else {
        for (int i = lo + t; i < hi; i += 1024) {
            const int2 e = ebuf[i];
            const unsigned x = (unsigned)e.x;
            const int pos = atomicAdd(&dcur[x >> 23], 1);
            ebuf2[lo + pos] = make_int2((int)(x & 0x7FFFFFu), e.y);
        }
        eptr = ebuf2 + lo;
    }
    __syncthreads();

    // --- gather: wave w handles dsts w, w+16, ... ---
    const int wid  = t >> 6;
    const int lane = t & 63;
    const int sub  = lane >> 3;   // edge slot 0..7
    const int l8   = lane & 7;    // 8-col group within row

    for (int d = wid; d < BSIZE; d += 16) {
        const int gd = b * BSIZE + d;
        if (gd >= n_nodes) break;
        const int cnt = dcnt[d];
        const int end = dscan[d];
        const int start = end - cnt;

        float acc[8] = {0.f,0.f,0.f,0.f,0.f,0.f,0.f,0.f};
        float denom = 0.f;
        int i = start + sub;
        for (; i + 8 < end; i += 16) {
            const int2 e0 = eptr[i];
            const int2 e1 = eptr[i + 8];
            const short8v z0 = *reinterpret_cast<const short8v*>(zb + (size_t)e0.x * N_OUT + l8 * 8);
            const short8v z1 = *reinterpret_cast<const short8v*>(zb + (size_t)e1.x * N_OUT + l8 * 8);
            const float p0 = __int_as_float(e0.y);
            const float p1 = __int_as_float(e1.y);
            denom += p0 + p1;
#pragma unroll
            for (int j = 0; j < 8; ++j) {
                acc[j] = fmaf(p0, bf16_to_f32(z0[j]), acc[j]);
                acc[j] = fmaf(p1, bf16_to_f32(z1[j]), acc[j]);
            }
        }
        for (; i < end; i += 8) {
            const int2 e0 = eptr[i];
            const short8v z0 = *reinterpret_cast<const short8v*>(zb + (size_t)e0.x * N_OUT + l8 * 8);
            const float p0 = __int_as_float(e0.y);
            denom += p0;
#pragma unroll
            for (int j = 0; j < 8; ++j)
                acc[j] = fmaf(p0, bf16_to_f32(z0[j]), acc[j]);
        }
#pragma unroll
        for (int off = 8; off < 64; off <<= 1) {
#pragma unroll
            for (int j = 0; j < 8; ++j)
                acc[j] += __shfl_xor(acc[j], off);
            denom += __shfl_xor(denom, off);
        }
        if (sub == 0) {
            const float inv = (cnt > 0) ? 1.f / denom : 0.f;
            float4 r0, r1;
            r0.x = acc[0] * inv; r0.y = acc[1] * inv; r0.z = acc[2] * inv; r0.w = acc[3] * inv;
            r1.x = acc[4] * inv; r1.y = acc[5] * inv; r1.z = acc[6] * inv; r1.w = acc[7] * inv;
            float4* po = reinterpret_cast<float4*>(out + (size_t)gd * N_OUT + l8 * 8);
            po[0] = r0; po[1] = r1;
        }
    }
}

// ---------------------------------------------------------------------------
extern "C" void kernel_launch(void* const* d_in, const int* in_sizes, int n_in,
                              void* d_out, int out_size, void* d_ws, size_t ws_size,
                              hipStream_t stream) {
    const float* h = (const float*)d_in[0];
    const float* W = (const float*)d_in[1];
    const float* A = (const float*)d_in[2];
    const int* src = (const int*)d_in[3];
    const int* dst = (const int*)d_in[4];
    float* out = (float*)d_out;

    const int n_nodes = in_sizes[0] / N_IN;
    const int n_edges = in_sizes[3];
    const int nbuck = (n_nodes + BSIZE - 1) / BSIZE;   // 391

    // workspace layout (16B alignment maintained)
    char* ws = (char*)d_ws;
    unsigned short* zb = (unsigned short*)ws;  ws += (size_t)n_nodes * N_OUT * 2;
    float* s_node  = (float*)ws;  ws += (size_t)n_nodes * 4;
    float* d_node  = (float*)ws;  ws += (size_t)n_nodes * 4;
    int*   bcount  = (int*)ws;    ws += MAXBUCK * 4;
    int*   bbase   = (int*)ws;    ws += (MAXBUCK + 2) * 4;
    int*   bcursor = (int*)ws;    ws += MAXBUCK * 4;
    ws = (char*)(((uintptr_t)ws + 15) & ~(uintptr_t)15);
    int2*  ebuf    = (int2*)ws;   ws += (size_t)n_edges * 8;
    int2*  ebuf2   = (int2*)ws;   // fallback only

    hipMemsetAsync(bcount, 0, MAXBUCK * sizeof(int), stream);

    // 1) GEMM + logits (z -> bf16)
    gemm_zsd_mfma<<<(n_nodes + GM - 1) / GM, 256, 0, stream>>>(h, W, A, zb, s_node, d_node, n_nodes);

    // 2) bucket histogram
    hist_bucket<<<256, 256, 0, stream>>>(dst, bcount, n_edges);

    // 3) bucket scan
    scan_buckets<<<1, 1024, 0, stream>>>(bcount, bbase, bcursor, nbuck, n_edges);

    // 4) bucket scatter (computes p, packs dlow|src)
    bucket_scatter<<<256, 256, 0, stream>>>(src, dst, s_node, d_node, bcursor, ebuf, n_edges, nbuck);

    // 5) merged bin + gather (LDS-staged edges)
    bucket_gather<<<nbuck, 1024, 0, stream>>>(ebuf, bbase, ebuf2, zb, out, n_nodes);
}